// Round 1
// 2278.068 us; speedup vs baseline: 2.1621x; 2.1621x over previous
//
#include <hip/hip_runtime.h>
#include <cstddef>
#include <cstdint>

// ---------------- dims ----------------
// B=1, S=1024, D=1024, H=16, G=4, HD=64, DFF=4096, V=32000, L=4
#define S_ 1024
#define D_ 1024
#define H_ 16
#define G_ 4
#define HD_ 64
#define DFF_ 4096
#define V_ 32000
#define L_ 4

typedef __bf16 v8bf __attribute__((ext_vector_type(8)));
typedef float f32x4 __attribute__((ext_vector_type(4)));

// RNE float->bf16 (bit trick; NaN edge irrelevant for this workload)
__device__ __forceinline__ unsigned short f2bf(float x) {
  unsigned u = __float_as_uint(x);
  return (unsigned short)((u + 0x7fffu + ((u >> 16) & 1u)) >> 16);
}

// ---------------- embedding gather (writes fp32 + bf16) ----------------
__global__ __launch_bounds__(256) void embed_k(const int* __restrict__ x,
                                               const float* __restrict__ emb,
                                               float* __restrict__ Hv,
                                               unsigned short* __restrict__ Hb) {
  int s = blockIdx.x;
  int r = x[s];
  float4 v = ((const float4*)(emb + (size_t)r * D_))[threadIdx.x];
  ((float4*)(Hv + (size_t)s * D_))[threadIdx.x] = v;
  ((ushort4*)(Hb + (size_t)s * D_))[threadIdx.x] =
      make_ushort4(f2bf(v.x), f2bf(v.y), f2bf(v.z), f2bf(v.w));
}

// ---------------- fp32 -> bf16 conversion (grid-stride, 8 elems/thread) ----------------
__global__ __launch_bounds__(256) void f2b_k(const float* __restrict__ in,
                                             unsigned short* __restrict__ out,
                                             int n8) {
  int stride = gridDim.x * 256;
  for (int i = blockIdx.x * 256 + threadIdx.x; i < n8; i += stride) {
    const float4* p = (const float4*)in + 2 * (size_t)i;
    float4 a = p[0], b = p[1];
    ((ushort4*)out)[2 * (size_t)i + 0] = make_ushort4(f2bf(a.x), f2bf(a.y), f2bf(a.z), f2bf(a.w));
    ((ushort4*)out)[2 * (size_t)i + 1] = make_ushort4(f2bf(b.x), f2bf(b.y), f2bf(b.z), f2bf(b.w));
  }
}

// ---------------- bf16 MFMA NT GEMM: C[m,n] = sum_k A[m,k]*B[n,k], fp32 epilogue ----------------
// A: (M,K) bf16 row-major, B: (N,K) bf16 row-major. M,N mult of 128; K mult of 64.
// m97 structure: 128x128 tile, BK=64, 4 waves (2x2), each wave 4x4 frags of 16x16x32.
// Staging: global_load_lds dwordx4, linear LDS dest; XOR-(row&7) swizzle applied to the
// GLOBAL source chunk index and to the ds_read address (both-sides involution, rule 21).
// ds_read bank check: lanes 0..15 read rows r..r+15 (row stride 128B = full bank cycle),
// chunk index (kq ^ (row&7)) cycles all 8 16B slots -> 2-way only (free).
__global__ __launch_bounds__(256) void gemm_bf16(const unsigned short* __restrict__ A,
                                                 const unsigned short* __restrict__ B,
                                                 const float* __restrict__ bias,
                                                 const float* __restrict__ colscale,
                                                 float smul,
                                                 float* __restrict__ C,
                                                 int M, int N, int K) {
  (void)M;
  __shared__ unsigned short As[128 * 64];  // 16 KB
  __shared__ unsigned short Bs[128 * 64];  // 16 KB
  const int tid = threadIdx.x;
  const int w = tid >> 6;
  const int l = tid & 63;
  const int wm = w >> 1, wn = w & 1;       // 2x2 wave grid, 64x64 per wave
  const size_t row0 = (size_t)blockIdx.y * 128;
  const size_t col0 = (size_t)blockIdx.x * 128;
  const int fr = l & 15;
  const int kq0 = l >> 4;                  // 0..3 k-group within 32-slab

  f32x4 acc[4][4];
#pragma unroll
  for (int i = 0; i < 4; ++i)
#pragma unroll
    for (int j = 0; j < 4; ++j) acc[i][j] = (f32x4){0.f, 0.f, 0.f, 0.f};

  for (int k0 = 0; k0 < K; k0 += 64) {
    // stage A and B tiles: 128 rows x 64 bf16 = 1024 chunks of 16B each, 4 passes x 256 thr
#pragma unroll
    for (int p = 0; p < 4; ++p) {
      const int id = p * 256 + tid;        // chunk id 0..1023
      const int row = id >> 3;             // tile row
      const int kbs = (id & 7) ^ (row & 7);  // inverse-swizzled source chunk
      __builtin_amdgcn_global_load_lds(
          (const __attribute__((address_space(1))) void*)(A + (row0 + row) * K + k0 + kbs * 8),
          (__attribute__((address_space(3))) void*)(As + (size_t)(p * 256 + w * 64) * 8), 16, 0, 0);
      __builtin_amdgcn_global_load_lds(
          (const __attribute__((address_space(1))) void*)(B + (col0 + row) * K + k0 + kbs * 8),
          (__attribute__((address_space(3))) void*)(Bs + (size_t)(p * 256 + w * 64) * 8), 16, 0, 0);
    }
    __syncthreads();   // compiler drains vmcnt before barrier
#pragma unroll
    for (int ks = 0; ks < 2; ++ks) {       // two K=32 slabs
      v8bf af[4], bfv[4];
      const int kq = ks * 4 + kq0;         // chunk column 0..7
#pragma unroll
      for (int i = 0; i < 4; ++i) {
        const int ar = wm * 64 + i * 16 + fr;
        af[i] = *(const v8bf*)(As + ar * 64 + ((kq ^ (ar & 7)) << 3));
        const int br = wn * 64 + i * 16 + fr;
        bfv[i] = *(const v8bf*)(Bs + br * 64 + ((kq ^ (br & 7)) << 3));
      }
#pragma unroll
      for (int i = 0; i < 4; ++i)
#pragma unroll
        for (int j = 0; j < 4; ++j)
          acc[i][j] = __builtin_amdgcn_mfma_f32_16x16x32_bf16(af[i], bfv[j], acc[i][j], 0, 0, 0);
    }
    __syncthreads();
  }

  // epilogue: D layout col=lane&15, row=(lane>>4)*4+reg (m89-verified)
  const int rb = (l >> 4) * 4;
#pragma unroll
  for (int j = 0; j < 4; ++j) {
    const size_t col = col0 + wn * 64 + j * 16 + fr;
    const float bb = bias[col];
    const float cs = (colscale ? colscale[col] : 1.f) * smul;
#pragma unroll
    for (int i = 0; i < 4; ++i) {
      const size_t rowb = row0 + wm * 64 + i * 16 + rb;
#pragma unroll
      for (int r = 0; r < 4; ++r)
        C[(rowb + r) * N + col] = (acc[i][j][r] + bb) * cs;
    }
  }
}

// ---------------- fused RoPE + cosine_norm (+ folded eff^2 * rtd for Q) ----------------
__global__ __launch_bounds__(256) void rope_norm(float* __restrict__ X,
                                                 const float* __restrict__ sqk,
                                                 int NH, float rtd) {
  const int idx = blockIdx.x * 4 + (threadIdx.x >> 6);
  const int lane = threadIdx.x & 63;
  const int s = idx / NH, hh = idx - s * NH;
  float* px = X + (size_t)s * NH * 64 + hh * 64;
  float x = px[lane];
  float other = px[lane ^ 32];
  int j = lane & 31;
  float inv = expf(-(float)j * 0.28782313662425572f);  // ln(10000)/32
  float ang = (float)s * inv;
  float c = cosf(ang), sn = sinf(ang);
  float rot = (lane < 32) ? -other : other;
  float val = fmaf(x, c, rot * sn);
  float ssq = val * val;
#pragma unroll
  for (int off = 32; off; off >>= 1) ssq += __shfl_xor(ssq, off);
  float scale = 1.0f / fmaxf(sqrtf(ssq), 1e-6f);
  if (sqk) {
    float eff = sqk[hh * 64 + lane] * rtd;
    scale *= eff * eff * rtd;
  }
  px[lane] = val * scale;
}

// ---------------- flash attention (fp32), 1 wave per query row ----------------
__global__ __launch_bounds__(256) void attn_fa(const float* __restrict__ Q,
                                               const float* __restrict__ Kn,
                                               const float* __restrict__ Vr,
                                               float* __restrict__ O) {
  const int head = blockIdx.x;
  const int g = head >> 2;               // HPG = 4
  const int qbase = blockIdx.y * 4;
  const int w = threadIdx.x >> 6, lane = threadIdx.x & 63;
  const int qrow = qbase + w;
  __shared__ float Ks[64][65], Vs[64][65];
  __shared__ float Qs[4][64], Ps[4][64];
  Qs[w][lane] = Q[(size_t)qrow * (H_ * 64) + head * 64 + lane];
  float m = -1e30f, l = 0.f, acc = 0.f;
  const int kbmax = qbase >> 6;
  const int sr = threadIdx.x >> 2;
  const int sc = (threadIdx.x & 3) * 16;
  for (int kb = 0; kb <= kbmax; ++kb) {
    __syncthreads();
    const float* krow = Kn + (size_t)(kb * 64 + sr) * (G_ * 64) + g * 64 + sc;
    const float* vrow = Vr + (size_t)(kb * 64 + sr) * (G_ * 64) + g * 64 + sc;
#pragma unroll
    for (int jj = 0; jj < 4; ++jj) {
      float4 kv = *(const float4*)(krow + jj * 4);
      Ks[sr][sc + jj * 4 + 0] = kv.x; Ks[sr][sc + jj * 4 + 1] = kv.y;
      Ks[sr][sc + jj * 4 + 2] = kv.z; Ks[sr][sc + jj * 4 + 3] = kv.w;
      float4 vv = *(const float4*)(vrow + jj * 4);
      Vs[sr][sc + jj * 4 + 0] = vv.x; Vs[sr][sc + jj * 4 + 1] = vv.y;
      Vs[sr][sc + jj * 4 + 2] = vv.z; Vs[sr][sc + jj * 4 + 3] = vv.w;
    }
    __syncthreads();
    float s = 0.f;
#pragma unroll 8
    for (int d = 0; d < 64; ++d) s = fmaf(Qs[w][d], Ks[lane][d], s);
    if (kb * 64 + lane > qrow) s = -1e30f;
    float bm = s;
#pragma unroll
    for (int off = 32; off; off >>= 1) bm = fmaxf(bm, __shfl_xor(bm, off));
    float mnew = fmaxf(m, bm);
    float alpha = __expf(m - mnew);
    float p = __expf(s - mnew);
    float ps = p;
#pragma unroll
    for (int off = 32; off; off >>= 1) ps += __shfl_xor(ps, off);
    l = l * alpha + ps;
    m = mnew;
    Ps[w][lane] = p;
    acc *= alpha;
#pragma unroll 8
    for (int kk = 0; kk < 64; ++kk) acc = fmaf(Ps[w][kk], Vs[kk][lane], acc);
  }
  O[(size_t)qrow * (H_ * 64) + head * 64 + lane] = acc / l;
}

// ---------------- residual + double cosine_norm, writes fp32 + bf16 ----------------
__global__ __launch_bounds__(256) void resid_norm(float* __restrict__ H,
                                                  unsigned short* __restrict__ Hb,
                                                  const float* __restrict__ Xin,
                                                  const float* __restrict__ eig,
                                                  float rtD) {
  const int row = blockIdx.x, t = threadIdx.x;
  __shared__ float sm1[4], sm2[4];
  float4 xv = *(const float4*)(Xin + (size_t)row * D_ + t * 4);
  float4 hv = *(const float4*)(H + (size_t)row * D_ + t * 4);
  float ss = xv.x * xv.x + xv.y * xv.y + xv.z * xv.z + xv.w * xv.w;
#pragma unroll
  for (int off = 32; off; off >>= 1) ss += __shfl_xor(ss, off);
  if ((t & 63) == 0) sm1[t >> 6] = ss;
  __syncthreads();
  ss = sm1[0] + sm1[1] + sm1[2] + sm1[3];
  float inv1 = 1.0f / fmaxf(sqrtf(ss), 1e-6f);
  float4 ev = *(const float4*)(eig + t * 4);
  float y[4];
  y[0] = hv.x + ev.x * rtD * (xv.x * inv1 - hv.x);
  y[1] = hv.y + ev.y * rtD * (xv.y * inv1 - hv.y);
  y[2] = hv.z + ev.z * rtD * (xv.z * inv1 - hv.z);
  y[3] = hv.w + ev.w * rtD * (xv.w * inv1 - hv.w);
  float s2 = y[0] * y[0] + y[1] * y[1] + y[2] * y[2] + y[3] * y[3];
#pragma unroll
  for (int off = 32; off; off >>= 1) s2 += __shfl_xor(s2, off);
  if ((t & 63) == 0) sm2[t >> 6] = s2;
  __syncthreads();
  s2 = sm2[0] + sm2[1] + sm2[2] + sm2[3];
  float inv2 = 1.0f / fmaxf(sqrtf(s2), 1e-6f);
  float4 o = make_float4(y[0] * inv2, y[1] * inv2, y[2] * inv2, y[3] * inv2);
  *(float4*)(H + (size_t)row * D_ + t * 4) = o;
  ((ushort4*)(Hb + (size_t)row * D_))[t] =
      make_ushort4(f2bf(o.x), f2bf(o.y), f2bf(o.z), f2bf(o.w));
}

// ---------------- swiglu: Ub = bf16(U * silu(G)) ----------------
__global__ __launch_bounds__(256) void swiglu(const float* __restrict__ U,
                                              const float* __restrict__ Gt,
                                              unsigned short* __restrict__ Ub) {
  int i = blockIdx.x * 256 + threadIdx.x;
  float4 u = ((const float4*)U)[i];
  float4 g = ((const float4*)Gt)[i];
  u.x *= g.x / (1.f + __expf(-g.x));
  u.y *= g.y / (1.f + __expf(-g.y));
  u.z *= g.z / (1.f + __expf(-g.z));
  u.w *= g.w / (1.f + __expf(-g.w));
  ((ushort4*)Ub)[i] = make_ushort4(f2bf(u.x), f2bf(u.y), f2bf(u.z), f2bf(u.w));
}

// ---------------- row softmax over V=32000 ----------------
__global__ __launch_bounds__(256) void softmax_rows(float* __restrict__ X, int N) {
  const int row = blockIdx.x, t = threadIdx.x;
  float* xr = X + (size_t)row * N;
  __shared__ float sm1[4], sm2[4];
  float m = -1e30f;
  for (int c = t; c < N; c += 256) m = fmaxf(m, xr[c]);
#pragma unroll
  for (int off = 32; off; off >>= 1) m = fmaxf(m, __shfl_xor(m, off));
  if ((t & 63) == 0) sm1[t >> 6] = m;
  __syncthreads();
  m = fmaxf(fmaxf(sm1[0], sm1[1]), fmaxf(sm1[2], sm1[3]));
  float l = 0.f;
  for (int c = t; c < N; c += 256) l += __expf(xr[c] - m);
#pragma unroll
  for (int off = 32; off; off >>= 1) l += __shfl_xor(l, off);
  if ((t & 63) == 0) sm2[t >> 6] = l;
  __syncthreads();
  l = sm2[0] + sm2[1] + sm2[2] + sm2[3];
  float inv = 1.0f / l;
  for (int c = t; c < N; c += 256) xr[c] = __expf(xr[c] - m) * inv;
}

// ---------------- launch ----------------
extern "C" void kernel_launch(void* const* d_in, const int* in_sizes, int n_in,
                              void* d_out, int out_size, void* d_ws, size_t ws_size,
                              hipStream_t stream) {
  (void)in_sizes; (void)n_in; (void)out_size; (void)ws_size;
  const int*   x      = (const int*)d_in[0];
  const float* emb    = (const float*)d_in[1];
  const float* qw     = (const float*)d_in[2];
  const float* qbias  = (const float*)d_in[3];
  const float* kw     = (const float*)d_in[4];
  const float* kbias  = (const float*)d_in[5];
  const float* vw     = (const float*)d_in[6];
  const float* vbias  = (const float*)d_in[7];
  const float* sqk    = (const float*)d_in[8];
  const float* ow     = (const float*)d_in[9];
  const float* obias  = (const float*)d_in[10];
  const float* w_in   = (const float*)d_in[11];
  const float* b_in   = (const float*)d_in[12];
  const float* w_gate = (const float*)d_in[13];
  const float* b_gate = (const float*)d_in[14];
  const float* w_out  = (const float*)d_in[15];
  const float* b_out  = (const float*)d_in[16];
  const float* s_u    = (const float*)d_in[17];
  const float* s_v    = (const float*)d_in[18];
  const float* eig_a  = (const float*)d_in[19];
  const float* eig_m  = (const float*)d_in[20];
  const float* out_w  = (const float*)d_in[21];
  const float* out_b  = (const float*)d_in[22];
  const float* s_z    = (const float*)d_in[23];
  float* out = (float*)d_out;

  const float rtd = 8.0f;   // sqrt(HD)
  const float rtD = 32.0f;  // sqrt(D)

  // workspace layout: fp32 buffers (50 MB) then bf16 buffers (~78 MB)
  float* hbuf = (float*)d_ws;                   // S*D
  float* qbuf = hbuf + (size_t)S_ * D_;         // S*D
  float* kbuf = qbuf + (size_t)S_ * D_;         // S*G*HD
  float* vbuf = kbuf + (size_t)S_ * G_ * HD_;   // S*G*HD
  float* abuf = vbuf + (size_t)S_ * G_ * HD_;   // S*D
  float* tbuf = abuf + (size_t)S_ * D_;         // S*D
  float* ubuf = tbuf + (size_t)S_ * D_;         // S*DFF
  float* gbuf = ubuf + (size_t)S_ * DFF_;       // S*DFF
  unsigned short* hb  = (unsigned short*)(gbuf + (size_t)S_ * DFF_);  // S*D
  unsigned short* ab  = hb + (size_t)S_ * D_;                         // S*D
  unsigned short* ub  = ab + (size_t)S_ * D_;                         // S*DFF
  unsigned short* wbf = ub + (size_t)S_ * DFF_;                       // V*D (max weight)

  auto conv = [&](const float* src, size_t n, unsigned short* dst) {
    int n8 = (int)(n / 8);
    int grid = (n8 + 255) / 256;
    if (grid > 2048) grid = 2048;
    f2b_k<<<grid, 256, 0, stream>>>(src, dst, n8);
  };

  embed_k<<<S_, 256, 0, stream>>>(x, emb, hbuf, hb);

  for (int i = 0; i < L_; ++i) {
    // Q/K/V projections
    conv(qw + (size_t)i * D_ * D_, (size_t)D_ * D_, wbf);
    gemm_bf16<<<dim3(D_ / 128, S_ / 128), 256, 0, stream>>>(
        hb, wbf, qbias + (size_t)i * D_, nullptr, 1.0f, qbuf, S_, D_, D_);
    conv(kw + (size_t)i * G_ * HD_ * D_, (size_t)G_ * HD_ * D_, wbf);
    gemm_bf16<<<dim3(G_ * HD_ / 128, S_ / 128), 256, 0, stream>>>(
        hb, wbf, kbias + (size_t)i * G_ * HD_, nullptr, 1.0f, kbuf, S_, G_ * HD_, D_);
    conv(vw + (size_t)i * G_ * HD_ * D_, (size_t)G_ * HD_ * D_, wbf);
    gemm_bf16<<<dim3(G_ * HD_ / 128, S_ / 128), 256, 0, stream>>>(
        hb, wbf, vbias + (size_t)i * G_ * HD_, nullptr, 1.0f, vbuf, S_, G_ * HD_, D_);
    // RoPE + cosine norm
    rope_norm<<<S_ * H_ / 4, 256, 0, stream>>>(qbuf, sqk + (size_t)i * H_ * HD_, H_, rtd);
    rope_norm<<<S_ * G_ / 4, 256, 0, stream>>>(kbuf, nullptr, G_, rtd);
    // attention
    attn_fa<<<dim3(H_, S_ / 4), 256, 0, stream>>>(qbuf, kbuf, vbuf, abuf);
    // O projection
    conv(abuf, (size_t)S_ * D_, ab);
    conv(ow + (size_t)i * D_ * D_, (size_t)D_ * D_, wbf);
    gemm_bf16<<<dim3(D_ / 128, S_ / 128), 256, 0, stream>>>(
        ab, wbf, obias + (size_t)i * D_, nullptr, 1.0f, tbuf, S_, D_, D_);
    resid_norm<<<S_, 256, 0, stream>>>(hbuf, hb, tbuf, eig_a + (size_t)i * D_, rtD);
    // FFN
    conv(w_in + (size_t)i * DFF_ * D_, (size_t)DFF_ * D_, wbf);
    gemm_bf16<<<dim3(DFF_ / 128, S_ / 128), 256, 0, stream>>>(
        hb, wbf, b_in + (size_t)i * DFF_, s_u + (size_t)i * DFF_, 1.0f, ubuf, S_, DFF_, D_);
    conv(w_gate + (size_t)i * DFF_ * D_, (size_t)DFF_ * D_, wbf);
    gemm_bf16<<<dim3(DFF_ / 128, S_ / 128), 256, 0, stream>>>(
        hb, wbf, b_gate + (size_t)i * DFF_, s_v + (size_t)i * DFF_, rtD, gbuf, S_, DFF_, D_);
    swiglu<<<(S_ * DFF_) / 1024, 256, 0, stream>>>(ubuf, gbuf, ub);
    conv(w_out + (size_t)i * D_ * DFF_, (size_t)D_ * DFF_, wbf);
    gemm_bf16<<<dim3(D_ / 128, S_ / 128), 256, 0, stream>>>(
        ub, wbf, b_out + (size_t)i * D_, nullptr, 1.0f, tbuf, S_, D_, DFF_);
    resid_norm<<<S_, 256, 0, stream>>>(hbuf, hb, tbuf, eig_m + (size_t)i * D_, rtD);
  }

  // logits + softmax
  conv(out_w, (size_t)V_ * D_, wbf);
  gemm_bf16<<<dim3(V_ / 128, S_ / 128), 256, 0, stream>>>(
      hb, wbf, out_b, s_z, rtD, out, S_, V_, D_);
  softmax_rows<<<S_, 256, 0, stream>>>(out, V_);
}

// Round 2
// 1748.158 us; speedup vs baseline: 2.8175x; 1.3031x over previous
//
#include <hip/hip_runtime.h>
#include <cstddef>
#include <cstdint>

// ---------------- dims ----------------
// B=1, S=1024, D=1024, H=16, G=4, HD=64, DFF=4096, V=32000, L=4
#define S_ 1024
#define D_ 1024
#define H_ 16
#define G_ 4
#define HD_ 64
#define DFF_ 4096
#define V_ 32000
#define L_ 4

typedef __bf16 v8bf __attribute__((ext_vector_type(8)));
typedef float f32x4 __attribute__((ext_vector_type(4)));

// RNE float->bf16 (bit trick; NaN edge irrelevant for this workload)
__device__ __forceinline__ unsigned short f2bf(float x) {
  unsigned u = __float_as_uint(x);
  return (unsigned short)((u + 0x7fffu + ((u >> 16) & 1u)) >> 16);
}

// ---------------- embedding gather (writes fp32 + bf16) ----------------
__global__ __launch_bounds__(256) void embed_k(const int* __restrict__ x,
                                               const float* __restrict__ emb,
                                               float* __restrict__ Hv,
                                               unsigned short* __restrict__ Hb) {
  int s = blockIdx.x;
  int r = x[s];
  float4 v = ((const float4*)(emb + (size_t)r * D_))[threadIdx.x];
  ((float4*)(Hv + (size_t)s * D_))[threadIdx.x] = v;
  ((ushort4*)(Hb + (size_t)s * D_))[threadIdx.x] =
      make_ushort4(f2bf(v.x), f2bf(v.y), f2bf(v.z), f2bf(v.w));
}

// ---------------- fp32 -> bf16 conversion (grid-stride, 8 elems/thread) ----------------
__global__ __launch_bounds__(256) void f2b_k(const float* __restrict__ in,
                                             unsigned short* __restrict__ out,
                                             int n8) {
  int stride = gridDim.x * 256;
  for (int i = blockIdx.x * 256 + threadIdx.x; i < n8; i += stride) {
    const float4* p = (const float4*)in + 2 * (size_t)i;
    float4 a = p[0], b = p[1];
    ((ushort4*)out)[2 * (size_t)i + 0] = make_ushort4(f2bf(a.x), f2bf(a.y), f2bf(a.z), f2bf(a.w));
    ((ushort4*)out)[2 * (size_t)i + 1] = make_ushort4(f2bf(b.x), f2bf(b.y), f2bf(b.z), f2bf(b.w));
  }
}

// 3-segment conversion: a (na8), b (nb8), c (rest) -> contiguous out
__global__ __launch_bounds__(256) void f2b3_k(const float* __restrict__ a,
                                              const float* __restrict__ b,
                                              const float* __restrict__ c,
                                              int na8, int nb8,
                                              unsigned short* __restrict__ out,
                                              int total8) {
  int stride = gridDim.x * 256;
  for (int i = blockIdx.x * 256 + threadIdx.x; i < total8; i += stride) {
    const float* src;
    int j;
    if (i < na8) { src = a; j = i; }
    else if (i < na8 + nb8) { src = b; j = i - na8; }
    else { src = c; j = i - na8 - nb8; }
    float4 x = ((const float4*)src)[2 * (size_t)j];
    float4 y = ((const float4*)src)[2 * (size_t)j + 1];
    ((ushort4*)out)[2 * (size_t)i + 0] = make_ushort4(f2bf(x.x), f2bf(x.y), f2bf(x.z), f2bf(x.w));
    ((ushort4*)out)[2 * (size_t)i + 1] = make_ushort4(f2bf(y.x), f2bf(y.y), f2bf(y.z), f2bf(y.w));
  }
}

// ---------------- per-layer bias/scale concat ----------------
// qkvb[1536] = qb|kb|vb ; ffnb[8192] = b_in|b_gate ; ffns[8192] = s_u | s_v*rtD
__global__ __launch_bounds__(256) void prep_layer(const float* __restrict__ qb,
                                                  const float* __restrict__ kb,
                                                  const float* __restrict__ vb,
                                                  const float* __restrict__ bin,
                                                  const float* __restrict__ bgate,
                                                  const float* __restrict__ su,
                                                  const float* __restrict__ sv,
                                                  float rtD,
                                                  float* __restrict__ qkvb,
                                                  float* __restrict__ ffnb,
                                                  float* __restrict__ ffns) {
  int i = blockIdx.x * 256 + threadIdx.x;
  if (i < 1536)
    qkvb[i] = (i < 1024) ? qb[i] : ((i < 1280) ? kb[i - 1024] : vb[i - 1280]);
  if (i < 8192) {
    ffnb[i] = (i < 4096) ? bin[i] : bgate[i - 4096];
    ffns[i] = (i < 4096) ? su[i] : sv[i - 4096] * rtD;
  }
}

// ---------------- bf16 MFMA NT GEMM: C[m,n] = sum_k A[m,k]*B[n,k], fp32 epilogue ----------------
// A: (M,K) bf16 row-major, B: (N,K) bf16 row-major. M,N mult of 128; K mult of 64.
__global__ __launch_bounds__(256) void gemm_bf16(const unsigned short* __restrict__ A,
                                                 const unsigned short* __restrict__ B,
                                                 const float* __restrict__ bias,
                                                 const float* __restrict__ colscale,
                                                 float smul,
                                                 float* __restrict__ C,
                                                 int M, int N, int K) {
  (void)M;
  __shared__ unsigned short As[128 * 64];  // 16 KB
  __shared__ unsigned short Bs[128 * 64];  // 16 KB
  const int tid = threadIdx.x;
  const int w = tid >> 6;
  const int l = tid & 63;
  const int wm = w >> 1, wn = w & 1;       // 2x2 wave grid, 64x64 per wave
  const size_t row0 = (size_t)blockIdx.y * 128;
  const size_t col0 = (size_t)blockIdx.x * 128;
  const int fr = l & 15;
  const int kq0 = l >> 4;                  // 0..3 k-group within 32-slab

  f32x4 acc[4][4];
#pragma unroll
  for (int i = 0; i < 4; ++i)
#pragma unroll
    for (int j = 0; j < 4; ++j) acc[i][j] = (f32x4){0.f, 0.f, 0.f, 0.f};

  for (int k0 = 0; k0 < K; k0 += 64) {
#pragma unroll
    for (int p = 0; p < 4; ++p) {
      const int id = p * 256 + tid;        // chunk id 0..1023
      const int row = id >> 3;             // tile row
      const int kbs = (id & 7) ^ (row & 7);  // inverse-swizzled source chunk
      __builtin_amdgcn_global_load_lds(
          (const __attribute__((address_space(1))) void*)(A + (row0 + row) * K + k0 + kbs * 8),
          (__attribute__((address_space(3))) void*)(As + (size_t)(p * 256 + w * 64) * 8), 16, 0, 0);
      __builtin_amdgcn_global_load_lds(
          (const __attribute__((address_space(1))) void*)(B + (col0 + row) * K + k0 + kbs * 8),
          (__attribute__((address_space(3))) void*)(Bs + (size_t)(p * 256 + w * 64) * 8), 16, 0, 0);
    }
    __syncthreads();
#pragma unroll
    for (int ks = 0; ks < 2; ++ks) {       // two K=32 slabs
      v8bf af[4], bfv[4];
      const int kq = ks * 4 + kq0;         // chunk column 0..7
#pragma unroll
      for (int i = 0; i < 4; ++i) {
        const int ar = wm * 64 + i * 16 + fr;
        af[i] = *(const v8bf*)(As + ar * 64 + ((kq ^ (ar & 7)) << 3));
        const int br = wn * 64 + i * 16 + fr;
        bfv[i] = *(const v8bf*)(Bs + br * 64 + ((kq ^ (br & 7)) << 3));
      }
#pragma unroll
      for (int i = 0; i < 4; ++i)
#pragma unroll
        for (int j = 0; j < 4; ++j)
          acc[i][j] = __builtin_amdgcn_mfma_f32_16x16x32_bf16(af[i], bfv[j], acc[i][j], 0, 0, 0);
    }
    __syncthreads();
  }

  const int rb = (l >> 4) * 4;
#pragma unroll
  for (int j = 0; j < 4; ++j) {
    const size_t col = col0 + wn * 64 + j * 16 + fr;
    const float bb = bias[col];
    const float cs = (colscale ? colscale[col] : 1.f) * smul;
#pragma unroll
    for (int i = 0; i < 4; ++i) {
      const size_t rowb = row0 + wm * 64 + i * 16 + rb;
#pragma unroll
      for (int r = 0; r < 4; ++r)
        C[(rowb + r) * N + col] = (acc[i][j][r] + bb) * cs;
    }
  }
}

// ---------------- fused RoPE + cosine_norm (+ folded eff^2 * rtd for Q) ----------------
// X rows have stride `rstride` floats; head block at hh*64.
__global__ __launch_bounds__(256) void rope_norm(float* __restrict__ X,
                                                 const float* __restrict__ sqk,
                                                 int NH, int rstride, float rtd) {
  const int idx = blockIdx.x * 4 + (threadIdx.x >> 6);
  const int lane = threadIdx.x & 63;
  const int s = idx / NH, hh = idx - s * NH;
  float* px = X + (size_t)s * rstride + hh * 64;
  float x = px[lane];
  float other = px[lane ^ 32];
  int j = lane & 31;
  float inv = expf(-(float)j * 0.28782313662425572f);  // ln(10000)/32
  float ang = (float)s * inv;
  float c = cosf(ang), sn = sinf(ang);
  float rot = (lane < 32) ? -other : other;
  float val = fmaf(x, c, rot * sn);
  float ssq = val * val;
#pragma unroll
  for (int off = 32; off; off >>= 1) ssq += __shfl_xor(ssq, off);
  float scale = 1.0f / fmaxf(sqrtf(ssq), 1e-6f);
  if (sqk) {
    float eff = sqk[hh * 64 + lane] * rtd;
    scale *= eff * eff * rtd;
  }
  px[lane] = val * scale;
}

// ---------------- flash attention (fp32), 4 q-rows per wave, 16 per block ----------------
// QKV: (S,1536) = [q(1024) | k(256) | v(256)] fp32, rope/norm already applied.
// Output: bf16 (S, 1024). Heavy blocks (large qbase) dispatched first.
__global__ __launch_bounds__(256) void attn_fa(const float* __restrict__ QKV,
                                               unsigned short* __restrict__ Ob) {
  const int head = blockIdx.x;
  const int g = head >> 2;               // HPG = 4
  const int qbase = ((int)gridDim.y - 1 - blockIdx.y) * 16;
  const int tid = threadIdx.x;
  const int w = tid >> 6, lane = tid & 63;
  __shared__ float Ks[64][64];  // XOR-swizzled chunks (c ^ (row&15))
  __shared__ float Vs[64][64];  // linear
  __shared__ float Qs[16][64];
  __shared__ float Ps[16][64];
  // stage Q (16 rows x 64)
  {
    int r = tid >> 4, c = (tid & 15) * 4;
    *(float4*)&Qs[r][c] =
        *(const float4*)(QKV + (size_t)(qbase + r) * 1536 + head * 64 + c);
  }
  float m[4], l[4], acc[4];
#pragma unroll
  for (int qi = 0; qi < 4; ++qi) { m[qi] = -1e30f; l[qi] = 0.f; acc[qi] = 0.f; }
  const int q0 = qbase + w * 4;
  const int kbmax = qbase >> 6;
  const int sr = tid >> 2;               // stage row 0..63
  const int sc = tid & 3;                // 4 chunks of 4 floats each

  for (int kb = 0; kb <= kbmax; ++kb) {
    __syncthreads();
    const float* kr = QKV + (size_t)(kb * 64 + sr) * 1536 + 1024 + g * 64;
    const float* vr = kr + 256;
#pragma unroll
    for (int j = 0; j < 4; ++j) {
      int ch = sc * 4 + j;
      *(float4*)&Ks[sr][((ch ^ (sr & 15)) * 4)] = *(const float4*)(kr + ch * 4);
      *(float4*)&Vs[sr][ch * 4] = *(const float4*)(vr + ch * 4);
    }
    __syncthreads();
    // own K row -> regs (16 x ds_read_b128, bank-uniform via swizzle)
    float4 kreg[16];
#pragma unroll
    for (int c = 0; c < 16; ++c)
      kreg[c] = *(const float4*)&Ks[lane][((c ^ (lane & 15)) * 4)];
    // QK^T: 4 q-rows, 4 independent FMA chains
    float s[4] = {0.f, 0.f, 0.f, 0.f};
#pragma unroll
    for (int c = 0; c < 16; ++c) {
#pragma unroll
      for (int qi = 0; qi < 4; ++qi) {
        float4 qv = *(const float4*)&Qs[w * 4 + qi][c * 4];
        s[qi] = fmaf(qv.x, kreg[c].x, s[qi]);
        s[qi] = fmaf(qv.y, kreg[c].y, s[qi]);
        s[qi] = fmaf(qv.z, kreg[c].z, s[qi]);
        s[qi] = fmaf(qv.w, kreg[c].w, s[qi]);
      }
    }
    const int key = kb * 64 + lane;
    // online softmax per q-row
#pragma unroll
    for (int qi = 0; qi < 4; ++qi) {
      float sv = (key > q0 + qi) ? -1e30f : s[qi];
      float bm = sv;
#pragma unroll
      for (int off = 32; off; off >>= 1) bm = fmaxf(bm, __shfl_xor(bm, off));
      float mnew = fmaxf(m[qi], bm);
      float alpha = __expf(m[qi] - mnew);
      float p = __expf(sv - mnew);
      float ps = p;
#pragma unroll
      for (int off = 32; off; off >>= 1) ps += __shfl_xor(ps, off);
      l[qi] = l[qi] * alpha + ps;
      m[qi] = mnew;
      Ps[w * 4 + qi][lane] = p;      // wave-private row; in-wave RAW via waitcnt
      acc[qi] *= alpha;
    }
    // PV: acc[qi] over 64 keys; Ps as float4 broadcasts, Vs conflict-free b32
#pragma unroll 4
    for (int k4 = 0; k4 < 16; ++k4) {
      float4 pv0 = *(const float4*)&Ps[w * 4 + 0][k4 * 4];
      float4 pv1 = *(const float4*)&Ps[w * 4 + 1][k4 * 4];
      float4 pv2 = *(const float4*)&Ps[w * 4 + 2][k4 * 4];
      float4 pv3 = *(const float4*)&Ps[w * 4 + 3][k4 * 4];
#pragma unroll
      for (int j = 0; j < 4; ++j) {
        float v = Vs[k4 * 4 + j][lane];
        acc[0] = fmaf(((const float*)&pv0)[j], v, acc[0]);
        acc[1] = fmaf(((const float*)&pv1)[j], v, acc[1]);
        acc[2] = fmaf(((const float*)&pv2)[j], v, acc[2]);
        acc[3] = fmaf(((const float*)&pv3)[j], v, acc[3]);
      }
    }
  }
#pragma unroll
  for (int qi = 0; qi < 4; ++qi)
    Ob[(size_t)(q0 + qi) * 1024 + head * 64 + lane] = f2bf(acc[qi] / l[qi]);
}

// ---------------- residual + double cosine_norm, writes fp32 + bf16 ----------------
__global__ __launch_bounds__(256) void resid_norm(float* __restrict__ H,
                                                  unsigned short* __restrict__ Hb,
                                                  const float* __restrict__ Xin,
                                                  const float* __restrict__ eig,
                                                  float rtD) {
  const int row = blockIdx.x, t = threadIdx.x;
  __shared__ float sm1[4], sm2[4];
  float4 xv = *(const float4*)(Xin + (size_t)row * D_ + t * 4);
  float4 hv = *(const float4*)(H + (size_t)row * D_ + t * 4);
  float ss = xv.x * xv.x + xv.y * xv.y + xv.z * xv.z + xv.w * xv.w;
#pragma unroll
  for (int off = 32; off; off >>= 1) ss += __shfl_xor(ss, off);
  if ((t & 63) == 0) sm1[t >> 6] = ss;
  __syncthreads();
  ss = sm1[0] + sm1[1] + sm1[2] + sm1[3];
  float inv1 = 1.0f / fmaxf(sqrtf(ss), 1e-6f);
  float4 ev = *(const float4*)(eig + t * 4);
  float y[4];
  y[0] = hv.x + ev.x * rtD * (xv.x * inv1 - hv.x);
  y[1] = hv.y + ev.y * rtD * (xv.y * inv1 - hv.y);
  y[2] = hv.z + ev.z * rtD * (xv.z * inv1 - hv.z);
  y[3] = hv.w + ev.w * rtD * (xv.w * inv1 - hv.w);
  float s2 = y[0] * y[0] + y[1] * y[1] + y[2] * y[2] + y[3] * y[3];
#pragma unroll
  for (int off = 32; off; off >>= 1) s2 += __shfl_xor(s2, off);
  if ((t & 63) == 0) sm2[t >> 6] = s2;
  __syncthreads();
  s2 = sm2[0] + sm2[1] + sm2[2] + sm2[3];
  float inv2 = 1.0f / fmaxf(sqrtf(s2), 1e-6f);
  float4 o = make_float4(y[0] * inv2, y[1] * inv2, y[2] * inv2, y[3] * inv2);
  *(float4*)(H + (size_t)row * D_ + t * 4) = o;
  ((ushort4*)(Hb + (size_t)row * D_))[t] =
      make_ushort4(f2bf(o.x), f2bf(o.y), f2bf(o.z), f2bf(o.w));
}

// ---------------- swiglu on concat UG (S x 8192): Ub = bf16(u * silu(g)) ----------------
__global__ __launch_bounds__(256) void swiglu(const float* __restrict__ UG,
                                              unsigned short* __restrict__ Ub) {
  int i = blockIdx.x * 256 + threadIdx.x;   // over S*DFF/4 float4s
  int s = i >> 10;                          // DFF/4 = 1024 float4 per row
  int f4 = i & 1023;
  float4 u = *(const float4*)(UG + (size_t)s * 8192 + f4 * 4);
  float4 g = *(const float4*)(UG + (size_t)s * 8192 + 4096 + f4 * 4);
  u.x *= g.x / (1.f + __expf(-g.x));
  u.y *= g.y / (1.f + __expf(-g.y));
  u.z *= g.z / (1.f + __expf(-g.z));
  u.w *= g.w / (1.f + __expf(-g.w));
  ((ushort4*)Ub)[(size_t)s * 1024 + f4] = make_ushort4(f2bf(u.x), f2bf(u.y), f2bf(u.z), f2bf(u.w));
}

// ---------------- row softmax over V=32000 ----------------
__global__ __launch_bounds__(256) void softmax_rows(float* __restrict__ X, int N) {
  const int row = blockIdx.x, t = threadIdx.x;
  float* xr = X + (size_t)row * N;
  __shared__ float sm1[4], sm2[4];
  float m = -1e30f;
  for (int c = t; c < N; c += 256) m = fmaxf(m, xr[c]);
#pragma unroll
  for (int off = 32; off; off >>= 1) m = fmaxf(m, __shfl_xor(m, off));
  if ((t & 63) == 0) sm1[t >> 6] = m;
  __syncthreads();
  m = fmaxf(fmaxf(sm1[0], sm1[1]), fmaxf(sm1[2], sm1[3]));
  float l = 0.f;
  for (int c = t; c < N; c += 256) l += __expf(xr[c] - m);
#pragma unroll
  for (int off = 32; off; off >>= 1) l += __shfl_xor(l, off);
  if ((t & 63) == 0) sm2[t >> 6] = l;
  __syncthreads();
  l = sm2[0] + sm2[1] + sm2[2] + sm2[3];
  float inv = 1.0f / l;
  for (int c = t; c < N; c += 256) xr[c] = __expf(xr[c] - m) * inv;
}

// ---------------- launch ----------------
extern "C" void kernel_launch(void* const* d_in, const int* in_sizes, int n_in,
                              void* d_out, int out_size, void* d_ws, size_t ws_size,
                              hipStream_t stream) {
  (void)in_sizes; (void)n_in; (void)out_size; (void)ws_size;
  const int*   x      = (const int*)d_in[0];
  const float* emb    = (const float*)d_in[1];
  const float* qw     = (const float*)d_in[2];
  const float* qbias  = (const float*)d_in[3];
  const float* kw     = (const float*)d_in[4];
  const float* kbias  = (const float*)d_in[5];
  const float* vw     = (const float*)d_in[6];
  const float* vbias  = (const float*)d_in[7];
  const float* sqk    = (const float*)d_in[8];
  const float* ow     = (const float*)d_in[9];
  const float* obias  = (const float*)d_in[10];
  const float* w_in   = (const float*)d_in[11];
  const float* b_in   = (const float*)d_in[12];
  const float* w_gate = (const float*)d_in[13];
  const float* b_gate = (const float*)d_in[14];
  const float* w_out  = (const float*)d_in[15];
  const float* b_out  = (const float*)d_in[16];
  const float* s_u    = (const float*)d_in[17];
  const float* s_v    = (const float*)d_in[18];
  const float* eig_a  = (const float*)d_in[19];
  const float* eig_m  = (const float*)d_in[20];
  const float* out_w  = (const float*)d_in[21];
  const float* out_b  = (const float*)d_in[22];
  const float* s_z    = (const float*)d_in[23];
  float* out = (float*)d_out;

  const float rtd = 8.0f;   // sqrt(HD)
  const float rtD = 32.0f;  // sqrt(D)

  // workspace layout
  float* hbuf  = (float*)d_ws;                     // S*D
  float* qkvb  = hbuf + (size_t)S_ * D_;           // S*1536
  float* tbuf  = qkvb + (size_t)S_ * 1536;         // S*D
  float* ugbuf = tbuf + (size_t)S_ * D_;           // S*8192
  float* pqkv  = ugbuf + (size_t)S_ * 8192;        // 1536
  float* pffb  = pqkv + 1536;                      // 8192
  float* pffs  = pffb + 8192;                      // 8192
  unsigned short* hb  = (unsigned short*)(pffs + 8192);  // S*D
  unsigned short* ab  = hb + (size_t)S_ * D_;            // S*D
  unsigned short* ub  = ab + (size_t)S_ * D_;            // S*DFF
  unsigned short* wbf = ub + (size_t)S_ * DFF_;          // up to V*D shorts

  auto conv = [&](const float* src, size_t n, unsigned short* dst) {
    int n8 = (int)(n / 8);
    int grid = (n8 + 255) / 256;
    if (grid > 2048) grid = 2048;
    f2b_k<<<grid, 256, 0, stream>>>(src, dst, n8);
  };

  embed_k<<<S_, 256, 0, stream>>>(x, emb, hbuf, hb);

  const int qk8 = (D_ * D_) / 8;            // qw float8s
  const int kv8 = (G_ * HD_ * D_) / 8;      // kw/vw float8s
  const int ff8 = (DFF_ * D_) / 8;          // w_in/w_gate float8s

  for (int i = 0; i < L_; ++i) {
    prep_layer<<<32, 256, 0, stream>>>(
        qbias + (size_t)i * D_, kbias + (size_t)i * G_ * HD_, vbias + (size_t)i * G_ * HD_,
        b_in + (size_t)i * DFF_, b_gate + (size_t)i * DFF_,
        s_u + (size_t)i * DFF_, s_v + (size_t)i * DFF_, rtD, pqkv, pffb, pffs);
    // QKV fused projection (N = 1536)
    f2b3_k<<<768, 256, 0, stream>>>(qw + (size_t)i * D_ * D_,
                                    kw + (size_t)i * G_ * HD_ * D_,
                                    vw + (size_t)i * G_ * HD_ * D_,
                                    qk8, kv8, wbf, qk8 + 2 * kv8);
    gemm_bf16<<<dim3(1536 / 128, S_ / 128), 256, 0, stream>>>(
        hb, wbf, pqkv, nullptr, 1.0f, qkvb, S_, 1536, D_);
    rope_norm<<<S_ * H_ / 4, 256, 0, stream>>>(qkvb, sqk + (size_t)i * H_ * HD_, H_, 1536, rtd);
    rope_norm<<<S_ * G_ / 4, 256, 0, stream>>>(qkvb + 1024, nullptr, G_, 1536, rtd);
    attn_fa<<<dim3(H_, S_ / 16), 256, 0, stream>>>(qkvb, ab);
    // O projection
    conv(ow + (size_t)i * D_ * D_, (size_t)D_ * D_, wbf);
    gemm_bf16<<<dim3(D_ / 128, S_ / 128), 256, 0, stream>>>(
        ab, wbf, obias + (size_t)i * D_, nullptr, 1.0f, tbuf, S_, D_, D_);
    resid_norm<<<S_, 256, 0, stream>>>(hbuf, hb, tbuf, eig_a + (size_t)i * D_, rtD);
    // FFN fused in+gate (N = 8192)
    f2b3_k<<<2048, 256, 0, stream>>>(w_in + (size_t)i * DFF_ * D_,
                                     w_gate + (size_t)i * DFF_ * D_,
                                     w_gate + (size_t)i * DFF_ * D_,
                                     ff8, ff8, wbf, 2 * ff8);
    gemm_bf16<<<dim3(8192 / 128, S_ / 128), 256, 0, stream>>>(
        hb, wbf, pffb, pffs, 1.0f, ugbuf, S_, 8192, D_);
    swiglu<<<(S_ * DFF_) / 1024, 256, 0, stream>>>(ugbuf, ub);
    conv(w_out + (size_t)i * D_ * DFF_, (size_t)D_ * DFF_, wbf);
    gemm_bf16<<<dim3(D_ / 128, S_ / 128), 256, 0, stream>>>(
        ub, wbf, b_out + (size_t)i * D_, nullptr, 1.0f, tbuf, S_, D_, DFF_);
    resid_norm<<<S_, 256, 0, stream>>>(hbuf, hb, tbuf, eig_m + (size_t)i * D_, rtD);
  }

  // logits + softmax
  conv(out_w, (size_t)V_ * D_, wbf);
  gemm_bf16<<<dim3(V_ / 128, S_ / 128), 256, 0, stream>>>(
      hb, wbf, out_b, s_z, rtD, out, S_, V_, D_);
  softmax_rows<<<S_, 256, 0, stream>>>(out, V_);
}

// Round 4
// 1669.657 us; speedup vs baseline: 2.9500x; 1.0470x over previous
//
#include <hip/hip_runtime.h>
#include <cstddef>
#include <cstdint>

// ---------------- dims ----------------
// B=1, S=1024, D=1024, H=16, G=4, HD=64, DFF=4096, V=32000, L=4
#define S_ 1024
#define D_ 1024
#define H_ 16
#define G_ 4
#define HD_ 64
#define DFF_ 4096
#define V_ 32000
#define L_ 4

typedef __bf16 v8bf __attribute__((ext_vector_type(8)));
typedef float f32x4 __attribute__((ext_vector_type(4)));

// RNE float->bf16 (bit trick; NaN edge irrelevant for this workload)
__device__ __forceinline__ unsigned short f2bf(float x) {
  unsigned u = __float_as_uint(x);
  return (unsigned short)((u + 0x7fffu + ((u >> 16) & 1u)) >> 16);
}

// ---------------- embedding gather (writes fp32 + bf16) ----------------
__global__ __launch_bounds__(256) void embed_k(const int* __restrict__ x,
                                               const float* __restrict__ emb,
                                               float* __restrict__ Hv,
                                               unsigned short* __restrict__ Hb) {
  int s = blockIdx.x;
  int r = x[s];
  float4 v = ((const float4*)(emb + (size_t)r * D_))[threadIdx.x];
  ((float4*)(Hv + (size_t)s * D_))[threadIdx.x] = v;
  ((ushort4*)(Hb + (size_t)s * D_))[threadIdx.x] =
      make_ushort4(f2bf(v.x), f2bf(v.y), f2bf(v.z), f2bf(v.w));
}

// ---------------- fp32 -> bf16 conversion (grid-stride, 8 elems/thread) ----------------
__global__ __launch_bounds__(256) void f2b_k(const float* __restrict__ in,
                                             unsigned short* __restrict__ out,
                                             int n8) {
  int stride = gridDim.x * 256;
  for (int i = blockIdx.x * 256 + threadIdx.x; i < n8; i += stride) {
    const float4* p = (const float4*)in + 2 * (size_t)i;
    float4 a = p[0], b = p[1];
    ((ushort4*)out)[2 * (size_t)i + 0] = make_ushort4(f2bf(a.x), f2bf(a.y), f2bf(a.z), f2bf(a.w));
    ((ushort4*)out)[2 * (size_t)i + 1] = make_ushort4(f2bf(b.x), f2bf(b.y), f2bf(b.z), f2bf(b.w));
  }
}

// 3-segment conversion: a (na8), b (nb8), c (rest) -> contiguous out
__global__ __launch_bounds__(256) void f2b3_k(const float* __restrict__ a,
                                              const float* __restrict__ b,
                                              const float* __restrict__ c,
                                              int na8, int nb8,
                                              unsigned short* __restrict__ out,
                                              int total8) {
  int stride = gridDim.x * 256;
  for (int i = blockIdx.x * 256 + threadIdx.x; i < total8; i += stride) {
    const float* src;
    int j;
    if (i < na8) { src = a; j = i; }
    else if (i < na8 + nb8) { src = b; j = i - na8; }
    else { src = c; j = i - na8 - nb8; }
    float4 x = ((const float4*)src)[2 * (size_t)j];
    float4 y = ((const float4*)src)[2 * (size_t)j + 1];
    ((ushort4*)out)[2 * (size_t)i + 0] = make_ushort4(f2bf(x.x), f2bf(x.y), f2bf(x.z), f2bf(x.w));
    ((ushort4*)out)[2 * (size_t)i + 1] = make_ushort4(f2bf(y.x), f2bf(y.y), f2bf(y.z), f2bf(y.w));
  }
}

// ---------------- per-layer bias/scale concat ----------------
__global__ __launch_bounds__(256) void prep_layer(const float* __restrict__ qb,
                                                  const float* __restrict__ kb,
                                                  const float* __restrict__ vb,
                                                  const float* __restrict__ bin,
                                                  const float* __restrict__ bgate,
                                                  const float* __restrict__ su,
                                                  const float* __restrict__ sv,
                                                  float rtD,
                                                  float* __restrict__ qkvb,
                                                  float* __restrict__ ffnb,
                                                  float* __restrict__ ffns) {
  int i = blockIdx.x * 256 + threadIdx.x;
  if (i < 1536)
    qkvb[i] = (i < 1024) ? qb[i] : ((i < 1280) ? kb[i - 1024] : vb[i - 1280]);
  if (i < 8192) {
    ffnb[i] = (i < 4096) ? bin[i] : bgate[i - 4096];
    ffns[i] = (i < 4096) ? su[i] : sv[i - 4096] * rtD;
  }
}

// ---------------- bf16 MFMA NT GEMM with XCD-chunked swizzle ----------------
// A: (M,K) bf16 row-major, B: (N,K) bf16 row-major. M,N mult of 128; K mult of 64.
// Bijective XCD remap (m204): consecutive wgids within one XCD walk row-blocks fastest
// (column-major decode), so each XCD streams a contiguous set of B column-panels once
// and reuses them across all 8 row-blocks from its private L2.
// Optional fused softmax partials: per row, per 64-col wave slab, write (max, sum exp).
__global__ __launch_bounds__(256) void gemm_bf16(const unsigned short* __restrict__ A,
                                                 const unsigned short* __restrict__ B,
                                                 const float* __restrict__ bias,
                                                 const float* __restrict__ colscale,
                                                 float smul,
                                                 float* __restrict__ C,
                                                 float* __restrict__ pmax,
                                                 float* __restrict__ psum,
                                                 int P,   // partials per row = 2*gridDim.x
                                                 int M, int N, int K) {
  (void)M;
  __shared__ unsigned short As[128 * 64];  // 16 KB
  __shared__ unsigned short Bs[128 * 64];  // 16 KB
  const int tid = threadIdx.x;
  const int w = tid >> 6;
  const int l = tid & 63;
  const int wm = w >> 1, wn = w & 1;       // 2x2 wave grid, 64x64 per wave
  // XCD-chunked bijective swizzle
  const int nwg = (int)(gridDim.x * gridDim.y);
  const int orig = (int)(blockIdx.y * gridDim.x + blockIdx.x);
  const int qq = nwg >> 3, rr = nwg & 7;
  const int xcd = orig & 7, wi = orig >> 3;
  const int wgid = (xcd < rr ? xcd * (qq + 1) : rr * (qq + 1) + (xcd - rr) * qq) + wi;
  const int bx = wgid / (int)gridDim.y;
  const int by = wgid - bx * (int)gridDim.y;
  const size_t row0 = (size_t)by * 128;
  const size_t col0 = (size_t)bx * 128;
  const int fr = l & 15;
  const int kq0 = l >> 4;                  // 0..3 k-group within 32-slab

  f32x4 acc[4][4];
#pragma unroll
  for (int i = 0; i < 4; ++i)
#pragma unroll
    for (int j = 0; j < 4; ++j) acc[i][j] = (f32x4){0.f, 0.f, 0.f, 0.f};

  for (int k0 = 0; k0 < K; k0 += 64) {
#pragma unroll
    for (int p = 0; p < 4; ++p) {
      const int id = p * 256 + tid;        // chunk id 0..1023
      const int row = id >> 3;             // tile row
      const int kbs = (id & 7) ^ (row & 7);  // inverse-swizzled source chunk
      __builtin_amdgcn_global_load_lds(
          (const __attribute__((address_space(1))) void*)(A + (row0 + row) * K + k0 + kbs * 8),
          (__attribute__((address_space(3))) void*)(As + (size_t)(p * 256 + w * 64) * 8), 16, 0, 0);
      __builtin_amdgcn_global_load_lds(
          (const __attribute__((address_space(1))) void*)(B + (col0 + row) * K + k0 + kbs * 8),
          (__attribute__((address_space(3))) void*)(Bs + (size_t)(p * 256 + w * 64) * 8), 16, 0, 0);
    }
    __syncthreads();
#pragma unroll
    for (int ks = 0; ks < 2; ++ks) {       // two K=32 slabs
      v8bf af[4], bfv[4];
      const int kq = ks * 4 + kq0;         // chunk column 0..7
#pragma unroll
      for (int i = 0; i < 4; ++i) {
        const int ar = wm * 64 + i * 16 + fr;
        af[i] = *(const v8bf*)(As + ar * 64 + ((kq ^ (ar & 7)) << 3));
        const int br = wn * 64 + i * 16 + fr;
        bfv[i] = *(const v8bf*)(Bs + br * 64 + ((kq ^ (br & 7)) << 3));
      }
#pragma unroll
      for (int i = 0; i < 4; ++i)
#pragma unroll
        for (int j = 0; j < 4; ++j)
          acc[i][j] = __builtin_amdgcn_mfma_f32_16x16x32_bf16(af[i], bfv[j], acc[i][j], 0, 0, 0);
    }
    __syncthreads();
  }

  // epilogue: D layout col=lane&15, row=(lane>>4)*4+reg (m89-verified)
  const int rb = (l >> 4) * 4;
  float bb[4], cs[4];
#pragma unroll
  for (int j = 0; j < 4; ++j) {
    const size_t col = col0 + wn * 64 + j * 16 + fr;
    bb[j] = bias[col];
    cs[j] = (colscale ? colscale[col] : 1.f) * smul;
  }
#pragma unroll
  for (int i = 0; i < 4; ++i) {
    const size_t rowb = row0 + wm * 64 + i * 16 + rb;
#pragma unroll
    for (int r = 0; r < 4; ++r) {
      float v[4];
#pragma unroll
      for (int j = 0; j < 4; ++j) {
        v[j] = (acc[i][j][r] + bb[j]) * cs[j];
        C[(rowb + r) * N + col0 + wn * 64 + j * 16 + fr] = v[j];
      }
      if (pmax) {
        float rm = fmaxf(fmaxf(v[0], v[1]), fmaxf(v[2], v[3]));
#pragma unroll
        for (int off = 1; off < 16; off <<= 1) rm = fmaxf(rm, __shfl_xor(rm, off));
        float rs = __expf(v[0] - rm) + __expf(v[1] - rm) + __expf(v[2] - rm) + __expf(v[3] - rm);
#pragma unroll
        for (int off = 1; off < 16; off <<= 1) rs += __shfl_xor(rs, off);
        if (fr == 0) {
          const size_t pidx = (rowb + r) * P + bx * 2 + wn;
          pmax[pidx] = rm;
          psum[pidx] = rs;
        }
      }
    }
  }
}

// ---------------- softmax combine + normalize (one row per block) ----------------
// pmax/psum: [M][P] per-row partials. X: (M,N) logits in-place -> probabilities.
__global__ __launch_bounds__(256) void softmax_combine(float* __restrict__ X,
                                                       const float* __restrict__ pmax,
                                                       const float* __restrict__ psum,
                                                       int N, int P) {
  const int row = blockIdx.x, t = threadIdx.x;
  const int w = t >> 6, lane = t & 63;
  __shared__ float smm[4], sll[4];
  float m = -1e30f, l = 0.f;
  for (int p = t; p < P; p += 256) {
    float bm = pmax[(size_t)row * P + p];
    float bl = psum[(size_t)row * P + p];
    float M2 = fmaxf(m, bm);
    l = l * __expf(m - M2) + bl * __expf(bm - M2);
    m = M2;
  }
#pragma unroll
  for (int off = 32; off; off >>= 1) {
    float om = __shfl_xor(m, off), ol = __shfl_xor(l, off);
    float M2 = fmaxf(m, om);
    l = l * __expf(m - M2) + ol * __expf(om - M2);
    m = M2;
  }
  if (lane == 0) { smm[w] = m; sll[w] = l; }
  __syncthreads();
  m = smm[0]; l = sll[0];
#pragma unroll
  for (int k = 1; k < 4; ++k) {
    float M2 = fmaxf(m, smm[k]);
    l = l * __expf(m - M2) + sll[k] * __expf(smm[k] - M2);
    m = M2;
  }
  const float inv = 1.0f / l;
  float4* xr = (float4*)(X + (size_t)row * N);
  for (int c = t; c < N / 4; c += 256) {
    float4 v = xr[c];
    v.x = __expf(v.x - m) * inv;
    v.y = __expf(v.y - m) * inv;
    v.z = __expf(v.z - m) * inv;
    v.w = __expf(v.w - m) * inv;
    xr[c] = v;
  }
}

// ---------------- fused RoPE + cosine_norm (+ folded eff^2 * rtd for Q) ----------------
__global__ __launch_bounds__(256) void rope_norm(float* __restrict__ X,
                                                 const float* __restrict__ sqk,
                                                 int NH, int rstride, float rtd) {
  const int idx = blockIdx.x * 4 + (threadIdx.x >> 6);
  const int lane = threadIdx.x & 63;
  const int s = idx / NH, hh = idx - s * NH;
  float* px = X + (size_t)s * rstride + hh * 64;
  float x = px[lane];
  float other = px[lane ^ 32];
  int j = lane & 31;
  float inv = expf(-(float)j * 0.28782313662425572f);  // ln(10000)/32
  float ang = (float)s * inv;
  float c = cosf(ang), sn = sinf(ang);
  float rot = (lane < 32) ? -other : other;
  float val = fmaf(x, c, rot * sn);
  float ssq = val * val;
#pragma unroll
  for (int off = 32; off; off >>= 1) ssq += __shfl_xor(ssq, off);
  float scale = 1.0f / fmaxf(sqrtf(ssq), 1e-6f);
  if (sqk) {
    float eff = sqk[hh * 64 + lane] * rtd;
    scale *= eff * eff * rtd;
  }
  px[lane] = val * scale;
}

// ---------------- flash attention (fp32), 4 q-rows per wave, 16 per block ----------------
__global__ __launch_bounds__(256) void attn_fa(const float* __restrict__ QKV,
                                               unsigned short* __restrict__ Ob) {
  const int head = blockIdx.x;
  const int g = head >> 2;               // HPG = 4
  const int qbase = ((int)gridDim.y - 1 - blockIdx.y) * 16;
  const int tid = threadIdx.x;
  const int w = tid >> 6, lane = tid & 63;
  __shared__ float Ks[64][64];  // XOR-swizzled chunks (c ^ (row&15))
  __shared__ float Vs[64][64];  // linear
  __shared__ float Qs[16][64];
  __shared__ float Ps[16][64];
  {
    int r = tid >> 4, c = (tid & 15) * 4;
    *(float4*)&Qs[r][c] =
        *(const float4*)(QKV + (size_t)(qbase + r) * 1536 + head * 64 + c);
  }
  float m[4], l[4], acc[4];
#pragma unroll
  for (int qi = 0; qi < 4; ++qi) { m[qi] = -1e30f; l[qi] = 0.f; acc[qi] = 0.f; }
  const int q0 = qbase + w * 4;
  const int kbmax = qbase >> 6;
  const int sr = tid >> 2;
  const int sc = tid & 3;

  for (int kb = 0; kb <= kbmax; ++kb) {
    __syncthreads();
    const float* kr = QKV + (size_t)(kb * 64 + sr) * 1536 + 1024 + g * 64;
    const float* vr = kr + 256;
#pragma unroll
    for (int j = 0; j < 4; ++j) {
      int ch = sc * 4 + j;
      *(float4*)&Ks[sr][((ch ^ (sr & 15)) * 4)] = *(const float4*)(kr + ch * 4);
      *(float4*)&Vs[sr][ch * 4] = *(const float4*)(vr + ch * 4);
    }
    __syncthreads();
    float4 kreg[16];
#pragma unroll
    for (int c = 0; c < 16; ++c)
      kreg[c] = *(const float4*)&Ks[lane][((c ^ (lane & 15)) * 4)];
    float s[4] = {0.f, 0.f, 0.f, 0.f};
#pragma unroll
    for (int c = 0; c < 16; ++c) {
#pragma unroll
      for (int qi = 0; qi < 4; ++qi) {
        float4 qv = *(const float4*)&Qs[w * 4 + qi][c * 4];
        s[qi] = fmaf(qv.x, kreg[c].x, s[qi]);
        s[qi] = fmaf(qv.y, kreg[c].y, s[qi]);
        s[qi] = fmaf(qv.z, kreg[c].z, s[qi]);
        s[qi] = fmaf(qv.w, kreg[c].w, s[qi]);
      }
    }
    const int key = kb * 64 + lane;
#pragma unroll
    for (int qi = 0; qi < 4; ++qi) {
      float sv = (key > q0 + qi) ? -1e30f : s[qi];
      float bm = sv;
#pragma unroll
      for (int off = 32; off; off >>= 1) bm = fmaxf(bm, __shfl_xor(bm, off));
      float mnew = fmaxf(m[qi], bm);
      float alpha = __expf(m[qi] - mnew);
      float p = __expf(sv - mnew);
      float ps = p;
#pragma unroll
      for (int off = 32; off; off >>= 1) ps += __shfl_xor(ps, off);
      l[qi] = l[qi] * alpha + ps;
      m[qi] = mnew;
      Ps[w * 4 + qi][lane] = p;
      acc[qi] *= alpha;
    }
#pragma unroll 4
    for (int k4 = 0; k4 < 16; ++k4) {
      float4 pv0 = *(const float4*)&Ps[w * 4 + 0][k4 * 4];
      float4 pv1 = *(const float4*)&Ps[w * 4 + 1][k4 * 4];
      float4 pv2 = *(const float4*)&Ps[w * 4 + 2][k4 * 4];
      float4 pv3 = *(const float4*)&Ps[w * 4 + 3][k4 * 4];
#pragma unroll
      for (int j = 0; j < 4; ++j) {
        float v = Vs[k4 * 4 + j][lane];
        acc[0] = fmaf(((const float*)&pv0)[j], v, acc[0]);
        acc[1] = fmaf(((const float*)&pv1)[j], v, acc[1]);
        acc[2] = fmaf(((const float*)&pv2)[j], v, acc[2]);
        acc[3] = fmaf(((const float*)&pv3)[j], v, acc[3]);
      }
    }
  }
#pragma unroll
  for (int qi = 0; qi < 4; ++qi)
    Ob[(size_t)(q0 + qi) * 1024 + head * 64 + lane] = f2bf(acc[qi] / l[qi]);
}

// ---------------- residual + double cosine_norm, writes fp32 + bf16 ----------------
__global__ __launch_bounds__(256) void resid_norm(float* __restrict__ H,
                                                  unsigned short* __restrict__ Hb,
                                                  const float* __restrict__ Xin,
                                                  const float* __restrict__ eig,
                                                  float rtD) {
  const int row = blockIdx.x, t = threadIdx.x;
  __shared__ float sm1[4], sm2[4];
  float4 xv = *(const float4*)(Xin + (size_t)row * D_ + t * 4);
  float4 hv = *(const float4*)(H + (size_t)row * D_ + t * 4);
  float ss = xv.x * xv.x + xv.y * xv.y + xv.z * xv.z + xv.w * xv.w;
#pragma unroll
  for (int off = 32; off; off >>= 1) ss += __shfl_xor(ss, off);
  if ((t & 63) == 0) sm1[t >> 6] = ss;
  __syncthreads();
  ss = sm1[0] + sm1[1] + sm1[2] + sm1[3];
  float inv1 = 1.0f / fmaxf(sqrtf(ss), 1e-6f);
  float4 ev = *(const float4*)(eig + t * 4);
  float y[4];
  y[0] = hv.x + ev.x * rtD * (xv.x * inv1 - hv.x);
  y[1] = hv.y + ev.y * rtD * (xv.y * inv1 - hv.y);
  y[2] = hv.z + ev.z * rtD * (xv.z * inv1 - hv.z);
  y[3] = hv.w + ev.w * rtD * (xv.w * inv1 - hv.w);
  float s2 = y[0] * y[0] + y[1] * y[1] + y[2] * y[2] + y[3] * y[3];
#pragma unroll
  for (int off = 32; off; off >>= 1) s2 += __shfl_xor(s2, off);
  if ((t & 63) == 0) sm2[t >> 6] = s2;
  __syncthreads();
  s2 = sm2[0] + sm2[1] + sm2[2] + sm2[3];
  float inv2 = 1.0f / fmaxf(sqrtf(s2), 1e-6f);
  float4 o = make_float4(y[0] * inv2, y[1] * inv2, y[2] * inv2, y[3] * inv2);
  *(float4*)(H + (size_t)row * D_ + t * 4) = o;
  ((ushort4*)(Hb + (size_t)row * D_))[t] =
      make_ushort4(f2bf(o.x), f2bf(o.y), f2bf(o.z), f2bf(o.w));
}

// ---------------- swiglu on concat UG (S x 8192): Ub = bf16(u * silu(g)) ----------------
__global__ __launch_bounds__(256) void swiglu(const float* __restrict__ UG,
                                              unsigned short* __restrict__ Ub) {
  int i = blockIdx.x * 256 + threadIdx.x;   // over S*DFF/4 float4s
  int s = i >> 10;                          // DFF/4 = 1024 float4 per row
  int f4 = i & 1023;
  float4 u = *(const float4*)(UG + (size_t)s * 8192 + f4 * 4);
  float4 g = *(const float4*)(UG + (size_t)s * 8192 + 4096 + f4 * 4);
  u.x *= g.x / (1.f + __expf(-g.x));
  u.y *= g.y / (1.f + __expf(-g.y));
  u.z *= g.z / (1.f + __expf(-g.z));
  u.w *= g.w / (1.f + __expf(-g.w));
  ((ushort4*)Ub)[(size_t)s * 1024 + f4] = make_ushort4(f2bf(u.x), f2bf(u.y), f2bf(u.z), f2bf(u.w));
}

// ---------------- launch ----------------
extern "C" void kernel_launch(void* const* d_in, const int* in_sizes, int n_in,
                              void* d_out, int out_size, void* d_ws, size_t ws_size,
                              hipStream_t stream) {
  (void)in_sizes; (void)n_in; (void)out_size; (void)ws_size;
  const int*   x      = (const int*)d_in[0];
  const float* emb    = (const float*)d_in[1];
  const float* qw     = (const float*)d_in[2];
  const float* qbias  = (const float*)d_in[3];
  const float* kw     = (const float*)d_in[4];
  const float* kbias  = (const float*)d_in[5];
  const float* vw     = (const float*)d_in[6];
  const float* vbias  = (const float*)d_in[7];
  const float* sqk    = (const float*)d_in[8];
  const float* ow     = (const float*)d_in[9];
  const float* obias  = (const float*)d_in[10];
  const float* w_in   = (const float*)d_in[11];
  const float* b_in   = (const float*)d_in[12];
  const float* w_gate = (const float*)d_in[13];
  const float* b_gate = (const float*)d_in[14];
  const float* w_out  = (const float*)d_in[15];
  const float* b_out  = (const float*)d_in[16];
  const float* s_u    = (const float*)d_in[17];
  const float* s_v    = (const float*)d_in[18];
  const float* eig_a  = (const float*)d_in[19];
  const float* eig_m  = (const float*)d_in[20];
  const float* out_w  = (const float*)d_in[21];
  const float* out_b  = (const float*)d_in[22];
  const float* s_z    = (const float*)d_in[23];
  float* out = (float*)d_out;

  const float rtd = 8.0f;   // sqrt(HD)
  const float rtD = 32.0f;  // sqrt(D)

  // workspace layout — IDENTICAL footprint to the round-2 (passing) layout.
  // pmax/psum alias qkvb: qkvb (S*1536 floats = 6.3 MB) is dead after the last
  // attention; the logits GEMM reads only hb/wbf. Needed: 2*S*500 = 4.1 MB.
  float* hbuf  = (float*)d_ws;                     // S*D
  float* qkvb  = hbuf + (size_t)S_ * D_;           // S*1536
  float* tbuf  = qkvb + (size_t)S_ * 1536;         // S*D
  float* ugbuf = tbuf + (size_t)S_ * D_;           // S*8192
  float* pqkv  = ugbuf + (size_t)S_ * 8192;        // 1536
  float* pffb  = pqkv + 1536;                      // 8192
  float* pffs  = pffb + 8192;                      // 8192
  float* pmax  = qkvb;                             // aliased: S*500
  float* psum  = qkvb + (size_t)S_ * 500;          // aliased: S*500
  unsigned short* hb  = (unsigned short*)(pffs + 8192);  // S*D
  unsigned short* ab  = hb + (size_t)S_ * D_;            // S*D
  unsigned short* ub  = ab + (size_t)S_ * D_;            // S*DFF
  unsigned short* wbf = ub + (size_t)S_ * DFF_;          // up to V*D shorts

  auto conv = [&](const float* src, size_t n, unsigned short* dst) {
    int n8 = (int)(n / 8);
    int grid = (n8 + 255) / 256;
    if (grid > 2048) grid = 2048;
    f2b_k<<<grid, 256, 0, stream>>>(src, dst, n8);
  };

  embed_k<<<S_, 256, 0, stream>>>(x, emb, hbuf, hb);

  const int qk8 = (D_ * D_) / 8;            // qw float8s
  const int kv8 = (G_ * HD_ * D_) / 8;      // kw/vw float8s
  const int ff8 = (DFF_ * D_) / 8;          // w_in/w_gate float8s

  for (int i = 0; i < L_; ++i) {
    prep_layer<<<32, 256, 0, stream>>>(
        qbias + (size_t)i * D_, kbias + (size_t)i * G_ * HD_, vbias + (size_t)i * G_ * HD_,
        b_in + (size_t)i * DFF_, b_gate + (size_t)i * DFF_,
        s_u + (size_t)i * DFF_, s_v + (size_t)i * DFF_, rtD, pqkv, pffb, pffs);
    // QKV fused projection (N = 1536)
    f2b3_k<<<768, 256, 0, stream>>>(qw + (size_t)i * D_ * D_,
                                    kw + (size_t)i * G_ * HD_ * D_,
                                    vw + (size_t)i * G_ * HD_ * D_,
                                    qk8, kv8, wbf, qk8 + 2 * kv8);
    gemm_bf16<<<dim3(1536 / 128, S_ / 128), 256, 0, stream>>>(
        hb, wbf, pqkv, nullptr, 1.0f, qkvb, nullptr, nullptr, 0, S_, 1536, D_);
    rope_norm<<<S_ * H_ / 4, 256, 0, stream>>>(qkvb, sqk + (size_t)i * H_ * HD_, H_, 1536, rtd);
    rope_norm<<<S_ * G_ / 4, 256, 0, stream>>>(qkvb + 1024, nullptr, G_, 1536, rtd);
    attn_fa<<<dim3(H_, S_ / 16), 256, 0, stream>>>(qkvb, ab);
    // O projection
    conv(ow + (size_t)i * D_ * D_, (size_t)D_ * D_, wbf);
    gemm_bf16<<<dim3(D_ / 128, S_ / 128), 256, 0, stream>>>(
        ab, wbf, obias + (size_t)i * D_, nullptr, 1.0f, tbuf, nullptr, nullptr, 0, S_, D_, D_);
    resid_norm<<<S_, 256, 0, stream>>>(hbuf, hb, tbuf, eig_a + (size_t)i * D_, rtD);
    // FFN fused in+gate (N = 8192)
    f2b3_k<<<2048, 256, 0, stream>>>(w_in + (size_t)i * DFF_ * D_,
                                     w_gate + (size_t)i * DFF_ * D_,
                                     w_gate + (size_t)i * DFF_ * D_,
                                     ff8, ff8, wbf, 2 * ff8);
    gemm_bf16<<<dim3(8192 / 128, S_ / 128), 256, 0, stream>>>(
        hb, wbf, pffb, pffs, 1.0f, ugbuf, nullptr, nullptr, 0, S_, 8192, D_);
    swiglu<<<(S_ * DFF_) / 1024, 256, 0, stream>>>(ugbuf, ub);
    conv(w_out + (size_t)i * D_ * DFF_, (size_t)D_ * DFF_, wbf);
    gemm_bf16<<<dim3(D_ / 128, S_ / 128), 256, 0, stream>>>(
        ub, wbf, b_out + (size_t)i * D_, nullptr, 1.0f, tbuf, nullptr, nullptr, 0, S_, D_, DFF_);
    resid_norm<<<S_, 256, 0, stream>>>(hbuf, hb, tbuf, eig_m + (size_t)i * D_, rtD);
  }

  // logits (+ fused softmax partials) + combine/normalize
  conv(out_w, (size_t)V_ * D_, wbf);
  gemm_bf16<<<dim3(V_ / 128, S_ / 128), 256, 0, stream>>>(
      hb, wbf, out_b, s_z, rtD, out, pmax, psum, 500, S_, V_, D_);
  softmax_combine<<<S_, 256, 0, stream>>>(out, pmax, psum, V_, 500);
}